// Round 1
// baseline (780.907 us; speedup 1.0000x reference)
//
#include <hip/hip_runtime.h>

#define NN 50000
#define NE 800000
#define D 128
#define NEG 0.2f

// ---------------- CSR build ----------------

__global__ void hist_kernel(const int* __restrict__ dst, int* __restrict__ cnt) {
  int e = blockIdx.x * 256 + threadIdx.x;
  if (e < NE) atomicAdd(&cnt[dst[e]], 1);
}

__global__ __launch_bounds__(1024) void scan_kernel(const int* __restrict__ cnt,
                                                    int* __restrict__ rowptr) {
  __shared__ int sd[1024];
  const int t = threadIdx.x;
  int carry = 0;
  for (int base = 0; base < NN; base += 1024) {
    int i = base + t;
    int x = (i < NN) ? cnt[i] : 0;
    int acc = x;
    sd[t] = acc;
    __syncthreads();
    for (int off = 1; off < 1024; off <<= 1) {
      int y = (t >= off) ? sd[t - off] : 0;
      __syncthreads();
      acc += y;
      sd[t] = acc;
      __syncthreads();
    }
    if (i < NN) rowptr[i] = carry + acc - x;   // exclusive scan
    carry += sd[1023];
    __syncthreads();
  }
  if (t == 0) rowptr[NN] = carry;
}

__global__ void scatter_kernel(const int* __restrict__ src, const int* __restrict__ dst,
                               const int* __restrict__ rowptr, int* __restrict__ fill,
                               int* __restrict__ ssrc) {
  int e = blockIdx.x * 256 + threadIdx.x;
  if (e < NE) {
    int d = dst[e];
    int pos = rowptr[d] + atomicAdd(&fill[d], 1);
    ssrc[pos] = src[e];
  }
}

// ---------------- edge aggregation (mean of leaky(hq[dst]+hk[src])) ----------------

__global__ __launch_bounds__(128) void aggregate_kernel(
    const int* __restrict__ rowptr, const int* __restrict__ ssrc,
    const float* __restrict__ hq, const float* __restrict__ hk,
    const int* __restrict__ cnt, float* __restrict__ agg) {
  const int v = blockIdx.x;
  const int t = threadIdx.x;
  const int beg = rowptr[v];
  const int end = rowptr[v + 1];
  const float q = hq[(size_t)v * D + t];
  float acc = 0.f;
  for (int e = beg; e < end; ++e) {
    int s = ssrc[e];
    float m = q + hk[(size_t)s * D + t];
    acc += (m >= 0.f) ? m : NEG * m;
  }
  float dnm = fmaxf((float)cnt[v], 1.f);
  agg[(size_t)v * D + t] = acc / dnm;
}

// ---------------- fp32 GEMM: C[M x 128] = op(A[M x 128] @ W[128 x 128] + b) ----------------
// tile 64 rows x 128 cols per block, 256 threads, 4x8 micro-tile.
// In-place (C == A) is safe: each block reads only its own rows, and a
// __syncthreads() separates the k-loop reads from the epilogue stores.

template <bool LEAKY, bool ACCUM>
__global__ __launch_bounds__(256) void gemm128(const float* __restrict__ A,
                                               const float* __restrict__ W,
                                               const float* __restrict__ bias,
                                               float* __restrict__ C, int M) {
  __shared__ float Wl[D * D];  // 64 KiB
  const int t = threadIdx.x;
  for (int i = t * 4; i < D * D; i += 1024) {
    *(float4*)(Wl + i) = *(const float4*)(W + i);
  }
  __syncthreads();

  const int ty = t >> 4;       // 0..15 -> row group
  const int tx = t & 15;       // 0..15 -> col group
  const int row0 = blockIdx.x * 64 + ty * 4;
  const int col0 = tx * 8;

  int r0 = row0 + 0; if (r0 > M - 1) r0 = M - 1;
  int r1 = row0 + 1; if (r1 > M - 1) r1 = M - 1;
  int r2 = row0 + 2; if (r2 > M - 1) r2 = M - 1;
  int r3 = row0 + 3; if (r3 > M - 1) r3 = M - 1;
  const float* A0 = A + (size_t)r0 * D;
  const float* A1 = A + (size_t)r1 * D;
  const float* A2 = A + (size_t)r2 * D;
  const float* A3 = A + (size_t)r3 * D;

  float acc[4][8];
#pragma unroll
  for (int r = 0; r < 4; ++r)
#pragma unroll
    for (int c = 0; c < 8; ++c) acc[r][c] = 0.f;

#pragma unroll 8
  for (int k = 0; k < D; ++k) {
    float a0 = A0[k], a1 = A1[k], a2 = A2[k], a3 = A3[k];
    const float4 w0 = *(const float4*)(Wl + k * D + col0);
    const float4 w1 = *(const float4*)(Wl + k * D + col0 + 4);
    float wv[8] = {w0.x, w0.y, w0.z, w0.w, w1.x, w1.y, w1.z, w1.w};
#pragma unroll
    for (int c = 0; c < 8; ++c) {
      acc[0][c] += a0 * wv[c];
      acc[1][c] += a1 * wv[c];
      acc[2][c] += a2 * wv[c];
      acc[3][c] += a3 * wv[c];
    }
  }

  const float4 b0 = *(const float4*)(bias + col0);
  const float4 b1 = *(const float4*)(bias + col0 + 4);
  float bb[8] = {b0.x, b0.y, b0.z, b0.w, b1.x, b1.y, b1.z, b1.w};

  __syncthreads();  // in-place safety: all A reads done before any C store

#pragma unroll
  for (int r = 0; r < 4; ++r) {
    int row = row0 + r;
    if (row < M) {
      float o[8];
#pragma unroll
      for (int c = 0; c < 8; ++c) {
        float v = acc[r][c] + bb[c];
        if (LEAKY) v = (v >= 0.f) ? v : NEG * v;
        o[c] = v;
      }
      float* Cp = C + (size_t)row * D + col0;
      if (ACCUM) {
        float4 c0 = *(const float4*)(Cp);
        float4 c1 = *(const float4*)(Cp + 4);
        o[0] += c0.x; o[1] += c0.y; o[2] += c0.z; o[3] += c0.w;
        o[4] += c1.x; o[5] += c1.y; o[6] += c1.z; o[7] += c1.w;
      }
      float4 s0 = {o[0], o[1], o[2], o[3]};
      float4 s1 = {o[4], o[5], o[6], o[7]};
      *(float4*)(Cp) = s0;
      *(float4*)(Cp + 4) = s1;
    }
  }
}

// ---------------- launch ----------------

extern "C" void kernel_launch(void* const* d_in, const int* in_sizes, int n_in,
                              void* d_out, int out_size, void* d_ws, size_t ws_size,
                              hipStream_t stream) {
  const float* feats = (const float*)d_in[0];
  const float* Wq = (const float*)d_in[1];
  const float* bq = (const float*)d_in[2];
  const float* Wk = (const float*)d_in[3];
  const float* bk = (const float*)d_in[4];
  const float* Wr = (const float*)d_in[5];
  const float* br = (const float*)d_in[6];
  const float* Wro = (const float*)d_in[7];
  const float* bro = (const float*)d_in[8];
  const int* src = (const int*)d_in[9];
  const int* dst = (const int*)d_in[10];
  float* out = (float*)d_out;

  size_t off = 0;
  char* base = (char*)d_ws;
  auto alloc = [&](size_t bytes) -> void* {
    void* p = base + off;
    off += (bytes + 255) & ~(size_t)255;
    return p;
  };
  int* cnt = (int*)alloc((size_t)NN * 4);
  int* fill = (int*)alloc((size_t)NN * 4);
  int* rowptr = (int*)alloc((size_t)(NN + 1) * 4);
  int* ssrc = (int*)alloc((size_t)NE * 4);
  float* hq = (float*)alloc((size_t)NN * D * 4);
  float* hk = (float*)alloc((size_t)NN * D * 4);
  float* agg = (float*)alloc((size_t)NN * D * 4);

  hipMemsetAsync(cnt, 0, (size_t)NN * 4, stream);
  hipMemsetAsync(fill, 0, (size_t)NN * 4, stream);

  const int eb = (NE + 255) / 256;
  hist_kernel<<<eb, 256, 0, stream>>>(dst, cnt);
  scan_kernel<<<1, 1024, 0, stream>>>(cnt, rowptr);
  scatter_kernel<<<eb, 256, 0, stream>>>(src, dst, rowptr, fill, ssrc);

  const int gb = (NN + 63) / 64;
  // readout stage 0: out = feats @ Wro[0] + bro[0]
  gemm128<false, false><<<gb, 256, 0, stream>>>(feats, Wro, bro, out, NN);

  // ---- layer 0 (input = feats) ----
  gemm128<false, false><<<gb, 256, 0, stream>>>(feats, Wq, bq, hq, NN);
  gemm128<false, false><<<gb, 256, 0, stream>>>(feats, Wk, bk, hk, NN);
  aggregate_kernel<<<NN, 128, 0, stream>>>(rowptr, ssrc, hq, hk, cnt, agg);
  gemm128<true, false><<<gb, 256, 0, stream>>>(agg, Wr, br, agg, NN);  // h1 (in-place)
  gemm128<false, true><<<gb, 256, 0, stream>>>(agg, Wro + D * D, bro + D, out, NN);

  // ---- layer 1 (input = h1 in agg) ----
  gemm128<false, false><<<gb, 256, 0, stream>>>(agg, Wq + D * D, bq + D, hq, NN);
  gemm128<false, false><<<gb, 256, 0, stream>>>(agg, Wk + D * D, bk + D, hk, NN);
  aggregate_kernel<<<NN, 128, 0, stream>>>(rowptr, ssrc, hq, hk, cnt, agg);
  gemm128<true, false><<<gb, 256, 0, stream>>>(agg, Wr + D * D, br + D, agg, NN);  // h2
  gemm128<false, true><<<gb, 256, 0, stream>>>(agg, Wro + 2 * D * D, bro + 2 * D, out, NN);
}

// Round 2
// 415.200 us; speedup vs baseline: 1.8808x; 1.8808x over previous
//
#include <hip/hip_runtime.h>

#define NN 50000
#define NE 800000
#define D 128
#define NEG 0.2f
#define NB 196           // ceil(NN/256) for scan
#define KP 136           // padded LDS k-stride (bf16 elems) to break bank conflicts

typedef short bf8_t __attribute__((ext_vector_type(8)));   // 8 x bf16 bits (16 B)
typedef float f4_t __attribute__((ext_vector_type(4)));

__device__ __forceinline__ unsigned short f2bf(float f) {
  unsigned int u = __float_as_uint(f);
  unsigned int r = (u + 0x7FFF + ((u >> 16) & 1)) >> 16;  // RNE
  return (unsigned short)r;
}
__device__ __forceinline__ float bf2f(unsigned int bits16) {
  return __uint_as_float(bits16 << 16);
}

// ---------------- weight prep: fp32 W[k][n] -> bf16 WT[n][k], 9 matrices ----------------
__global__ __launch_bounds__(256) void prep_weights(
    const float* __restrict__ Wq, const float* __restrict__ Wk,
    const float* __restrict__ Wr, const float* __restrict__ Wro,
    unsigned short* __restrict__ WT) {
  const int m = blockIdx.y;
  const float* src;
  if (m < 2) src = Wq + m * D * D;
  else if (m < 4) src = Wk + (m - 2) * D * D;
  else if (m < 6) src = Wr + (m - 4) * D * D;
  else src = Wro + (m - 6) * D * D;
  unsigned short* dstp = WT + m * D * D;
  const int t = threadIdx.x;
  const int n = blockIdx.x * 2 + (t >> 7);
  const int k = t & 127;
  dstp[n * D + k] = f2bf(src[k * D + n]);
}

// ---------------- feats fp32 -> bf16 ----------------
__global__ __launch_bounds__(256) void convert_feats(const float* __restrict__ in,
                                                     unsigned short* __restrict__ out) {
  int i = (blockIdx.x * 256 + threadIdx.x) * 4;
  float4 v = *(const float4*)(in + i);
  ushort4 o = {f2bf(v.x), f2bf(v.y), f2bf(v.z), f2bf(v.w)};
  *(ushort4*)(out + i) = o;
}

// ---------------- CSR build ----------------
__global__ void hist_kernel(const int* __restrict__ dst, int* __restrict__ cnt) {
  int e = blockIdx.x * 256 + threadIdx.x;
  if (e < NE) atomicAdd(&cnt[dst[e]], 1);
}

__global__ __launch_bounds__(256) void scan_partial(const int* __restrict__ cnt,
                                                    int* __restrict__ bsum) {
  int i = blockIdx.x * 256 + threadIdx.x;
  int x = (i < NN) ? cnt[i] : 0;
  for (int off = 32; off; off >>= 1) x += __shfl_down(x, off, 64);
  __shared__ int ws_[4];
  if ((threadIdx.x & 63) == 0) ws_[threadIdx.x >> 6] = x;
  __syncthreads();
  if (threadIdx.x == 0) bsum[blockIdx.x] = ws_[0] + ws_[1] + ws_[2] + ws_[3];
}

__global__ __launch_bounds__(256) void scan_bsum(int* __restrict__ bsum) {
  __shared__ int sd[256];
  int t = threadIdx.x;
  int x = (t < NB) ? bsum[t] : 0;
  sd[t] = x;
  __syncthreads();
  int acc = x;
  for (int off = 1; off < 256; off <<= 1) {
    int y = (t >= off) ? sd[t - off] : 0;
    __syncthreads();
    acc += y;
    sd[t] = acc;
    __syncthreads();
  }
  if (t < NB) bsum[t] = acc - x;  // exclusive
}

__global__ __launch_bounds__(256) void scan_final(const int* __restrict__ cnt,
                                                  const int* __restrict__ bsum,
                                                  int* __restrict__ rowptr) {
  __shared__ int sd[256];
  int t = threadIdx.x;
  int i = blockIdx.x * 256 + t;
  int x = (i < NN) ? cnt[i] : 0;
  sd[t] = x;
  __syncthreads();
  int acc = x;
  for (int off = 1; off < 256; off <<= 1) {
    int y = (t >= off) ? sd[t - off] : 0;
    __syncthreads();
    acc += y;
    sd[t] = acc;
    __syncthreads();
  }
  if (i < NN) rowptr[i] = bsum[blockIdx.x] + acc - x;
  if (blockIdx.x == 0 && t == 0) rowptr[NN] = NE;
}

__global__ void scatter_kernel(const int* __restrict__ src, const int* __restrict__ dst,
                               const int* __restrict__ rowptr, int* __restrict__ fill,
                               int* __restrict__ ssrc) {
  int e = blockIdx.x * 256 + threadIdx.x;
  if (e < NE) {
    int d = dst[e];
    int pos = rowptr[d] + atomicAdd(&fill[d], 1);
    ssrc[pos] = src[e];
  }
}

// ---------------- aggregation: agg[v] = mean_e leaky(hq[v] + hk[src[e]]) (bf16 in/out) ----
__global__ __launch_bounds__(256) void aggregate_kernel(
    const int* __restrict__ rowptr, const int* __restrict__ ssrc,
    const unsigned short* __restrict__ hq, const unsigned short* __restrict__ hk,
    const int* __restrict__ cnt, unsigned short* __restrict__ agg) {
  const int v = blockIdx.x * 4 + (threadIdx.x >> 6);
  if (v >= NN) return;
  const int lane = threadIdx.x & 63;
  const int beg = rowptr[v];
  const int end = rowptr[v + 1];
  unsigned int qb = *(const unsigned int*)(hq + (size_t)v * D + lane * 2);
  const float q0 = bf2f(qb & 0xFFFFu);
  const float q1 = bf2f(qb >> 16);
  float a0 = 0.f, a1 = 0.f;
  int e = beg;
  for (; e + 4 <= end; e += 4) {
    int s0 = ssrc[e], s1 = ssrc[e + 1], s2 = ssrc[e + 2], s3 = ssrc[e + 3];
    unsigned int k0 = *(const unsigned int*)(hk + (size_t)s0 * D + lane * 2);
    unsigned int k1 = *(const unsigned int*)(hk + (size_t)s1 * D + lane * 2);
    unsigned int k2 = *(const unsigned int*)(hk + (size_t)s2 * D + lane * 2);
    unsigned int k3 = *(const unsigned int*)(hk + (size_t)s3 * D + lane * 2);
    float m;
    m = q0 + bf2f(k0 & 0xFFFFu); a0 += (m >= 0.f) ? m : NEG * m;
    m = q1 + bf2f(k0 >> 16);     a1 += (m >= 0.f) ? m : NEG * m;
    m = q0 + bf2f(k1 & 0xFFFFu); a0 += (m >= 0.f) ? m : NEG * m;
    m = q1 + bf2f(k1 >> 16);     a1 += (m >= 0.f) ? m : NEG * m;
    m = q0 + bf2f(k2 & 0xFFFFu); a0 += (m >= 0.f) ? m : NEG * m;
    m = q1 + bf2f(k2 >> 16);     a1 += (m >= 0.f) ? m : NEG * m;
    m = q0 + bf2f(k3 & 0xFFFFu); a0 += (m >= 0.f) ? m : NEG * m;
    m = q1 + bf2f(k3 >> 16);     a1 += (m >= 0.f) ? m : NEG * m;
  }
  for (; e < end; ++e) {
    int s = ssrc[e];
    unsigned int kb = *(const unsigned int*)(hk + (size_t)s * D + lane * 2);
    float m;
    m = q0 + bf2f(kb & 0xFFFFu); a0 += (m >= 0.f) ? m : NEG * m;
    m = q1 + bf2f(kb >> 16);     a1 += (m >= 0.f) ? m : NEG * m;
  }
  float dnm = fmaxf((float)cnt[v], 1.f);
  unsigned int ob = (unsigned int)f2bf(a0 / dnm) | ((unsigned int)f2bf(a1 / dnm) << 16);
  *(unsigned int*)(agg + (size_t)v * D + lane * 2) = ob;
}

// ---------------- bf16 MFMA GEMM: C[M x 128] = op(A[M x 128] @ W + b) ----------------
// A bf16 row-major, WT bf16 [n][k] (pre-transposed), 256 thr = 4 waves,
// 128 rows/block, each wave a 32x128 strip via 2x8 tiles of 16x16x32 MFMA.
template <bool LEAKY, bool OUTF32, bool ACCUM>
__global__ __launch_bounds__(256) void gemm_mfma(const unsigned short* __restrict__ A,
                                                 const unsigned short* __restrict__ WT,
                                                 const float* __restrict__ bias,
                                                 void* __restrict__ Cout, int M) {
  __shared__ unsigned short w[D * KP];
  const int t = threadIdx.x;
#pragma unroll
  for (int i = 0; i < 8; ++i) {
    int idx8 = t + i * 256;            // 0..2047 (16-byte chunks)
    int n = idx8 >> 4, k8 = (idx8 & 15) << 3;
    *(uint4*)(&w[n * KP + k8]) = *(const uint4*)(&WT[n * D + k8]);
  }
  __syncthreads();

  const int wave = t >> 6;
  const int lane = t & 63;
  const int l15 = lane & 15;
  const int quad = lane >> 4;
  const int row_base = blockIdx.x * 128 + wave * 32;

  f4_t acc[2][8] = {};
  int r0 = row_base + l15;      if (r0 >= M) r0 = M - 1;
  int r1 = row_base + 16 + l15; if (r1 >= M) r1 = M - 1;
  const unsigned short* A0 = A + (size_t)r0 * D + quad * 8;
  const unsigned short* A1 = A + (size_t)r1 * D + quad * 8;

#pragma unroll
  for (int kc = 0; kc < 4; ++kc) {
    bf8_t a0 = *(const bf8_t*)(A0 + kc * 32);
    bf8_t a1 = *(const bf8_t*)(A1 + kc * 32);
#pragma unroll
    for (int nt = 0; nt < 8; ++nt) {
      bf8_t b = *(const bf8_t*)(&w[(nt * 16 + l15) * KP + kc * 32 + quad * 8]);
      acc[0][nt] = __builtin_amdgcn_mfma_f32_16x16x32_bf16(a0, b, acc[0][nt], 0, 0, 0);
      acc[1][nt] = __builtin_amdgcn_mfma_f32_16x16x32_bf16(a1, b, acc[1][nt], 0, 0, 0);
    }
  }

#pragma unroll
  for (int rt = 0; rt < 2; ++rt) {
#pragma unroll
    for (int nt = 0; nt < 8; ++nt) {
      const int col = nt * 16 + l15;
      const float bcol = bias[col];
#pragma unroll
      for (int reg = 0; reg < 4; ++reg) {
        int row = row_base + rt * 16 + quad * 4 + reg;
        if (row < M) {
          float v = acc[rt][nt][reg] + bcol;
          if (LEAKY) v = (v >= 0.f) ? v : NEG * v;
          if (OUTF32) {
            float* Cp = (float*)Cout + (size_t)row * D + col;
            if (ACCUM) v += *Cp;
            *Cp = v;
          } else {
            ((unsigned short*)Cout)[(size_t)row * D + col] = f2bf(v);
          }
        }
      }
    }
  }
}

// ---------------- launch ----------------
extern "C" void kernel_launch(void* const* d_in, const int* in_sizes, int n_in,
                              void* d_out, int out_size, void* d_ws, size_t ws_size,
                              hipStream_t stream) {
  const float* feats = (const float*)d_in[0];
  const float* Wq = (const float*)d_in[1];
  const float* bq = (const float*)d_in[2];
  const float* Wk = (const float*)d_in[3];
  const float* bk = (const float*)d_in[4];
  const float* Wr = (const float*)d_in[5];
  const float* br = (const float*)d_in[6];
  const float* Wro = (const float*)d_in[7];
  const float* bro = (const float*)d_in[8];
  const int* src = (const int*)d_in[9];
  const int* dst = (const int*)d_in[10];
  float* out = (float*)d_out;

  size_t off = 0;
  char* base = (char*)d_ws;
  auto alloc = [&](size_t bytes) -> void* {
    void* p = base + off;
    off += (bytes + 255) & ~(size_t)255;
    return p;
  };
  int* cnt = (int*)alloc((size_t)NN * 4);
  int* fill = (int*)alloc((size_t)NN * 4);
  int* bsum = (int*)alloc((size_t)NB * 4);
  int* rowptr = (int*)alloc((size_t)(NN + 1) * 4);
  int* ssrc = (int*)alloc((size_t)NE * 4);
  unsigned short* WT = (unsigned short*)alloc((size_t)9 * D * D * 2);
  unsigned short* x0 = (unsigned short*)alloc((size_t)NN * D * 2);
  unsigned short* hq = (unsigned short*)alloc((size_t)NN * D * 2);
  unsigned short* hk = (unsigned short*)alloc((size_t)NN * D * 2);
  unsigned short* ag = (unsigned short*)alloc((size_t)NN * D * 2);
  unsigned short* h = (unsigned short*)alloc((size_t)NN * D * 2);

  hipMemsetAsync(cnt, 0, (size_t)NN * 4, stream);
  hipMemsetAsync(fill, 0, (size_t)NN * 4, stream);

  prep_weights<<<dim3(64, 9), 256, 0, stream>>>(Wq, Wk, Wr, Wro, WT);
  convert_feats<<<(NN * D / 4 + 255) / 256, 256, 0, stream>>>(feats, x0);

  const int eb = (NE + 255) / 256;
  hist_kernel<<<eb, 256, 0, stream>>>(dst, cnt);
  scan_partial<<<NB, 256, 0, stream>>>(cnt, bsum);
  scan_bsum<<<1, 256, 0, stream>>>(bsum);
  scan_final<<<NB, 256, 0, stream>>>(cnt, bsum, rowptr);
  scatter_kernel<<<eb, 256, 0, stream>>>(src, dst, rowptr, fill, ssrc);

  const int gb = (NN + 127) / 128;
  const int ab = (NN + 3) / 4;
  const size_t WM = (size_t)D * D;  // elems per weight matrix

  // readout stage 0: out = x0 @ Wro0 + bro0   (fp32 out, no accum)
  gemm_mfma<false, true, false><<<gb, 256, 0, stream>>>(x0, WT + 6 * WM, bro, out, NN);

  // ---- layer 0 ----
  gemm_mfma<false, false, false><<<gb, 256, 0, stream>>>(x0, WT + 0 * WM, bq, hq, NN);
  gemm_mfma<false, false, false><<<gb, 256, 0, stream>>>(x0, WT + 2 * WM, bk, hk, NN);
  aggregate_kernel<<<ab, 256, 0, stream>>>(rowptr, ssrc, hq, hk, cnt, ag);
  gemm_mfma<true, false, false><<<gb, 256, 0, stream>>>(ag, WT + 4 * WM, br, h, NN);
  gemm_mfma<false, true, true><<<gb, 256, 0, stream>>>(h, WT + 7 * WM, bro + D, out, NN);

  // ---- layer 1 ----
  gemm_mfma<false, false, false><<<gb, 256, 0, stream>>>(h, WT + 1 * WM, bq + D, hq, NN);
  gemm_mfma<false, false, false><<<gb, 256, 0, stream>>>(h, WT + 3 * WM, bk + D, hk, NN);
  aggregate_kernel<<<ab, 256, 0, stream>>>(rowptr, ssrc, hq, hk, cnt, ag);
  gemm_mfma<true, false, false><<<gb, 256, 0, stream>>>(ag, WT + 5 * WM, br + D, h, NN);
  gemm_mfma<false, true, true><<<gb, 256, 0, stream>>>(h, WT + 8 * WM, bro + 2 * D, out, NN);
}